// Round 1
// baseline (370.228 us; speedup 1.0000x reference)
//
#include <hip/hip_runtime.h>

typedef unsigned short u16;
typedef unsigned int u32;
typedef __bf16 bf16x8 __attribute__((ext_vector_type(8)));
typedef float f32x4 __attribute__((ext_vector_type(4)));

#define B_ROWS 16384
#define INSZ 512
#define HSZ 1024

__device__ __forceinline__ u16 f2bf(float f) {
  u32 u = __float_as_uint(f);
  u = (u + 0x7fffu + ((u >> 16) & 1u)) >> 16;  // RNE
  return (u16)u;
}
__device__ __forceinline__ float bf2f(u16 b) {
  return __uint_as_float(((u32)b) << 16);
}

__device__ __forceinline__ void gload_lds16(const void* g, void* l) {
  __builtin_amdgcn_global_load_lds((const __attribute__((address_space(1))) void*)g,
                                   (__attribute__((address_space(3))) void*)l,
                                   16, 0, 0);
}

// ---------------- converts ----------------
__global__ void cvt_bf16_kernel(const float* __restrict__ in, u16* __restrict__ out, int n) {
  int i = (blockIdx.x * blockDim.x + threadIdx.x) * 4;
  if (i >= n) return;
  float4 v = *(const float4*)(in + i);
  u32 a = (u32)f2bf(v.x) | ((u32)f2bf(v.y) << 16);
  u32 b = (u32)f2bf(v.z) | ((u32)f2bf(v.w) << 16);
  *(uint2*)(out + i) = make_uint2(a, b);
}

// W: K x N (f32, row-major) -> Wt: N x K (bf16, row-major)
__global__ void transpose_cvt_kernel(const float* __restrict__ W, u16* __restrict__ Wt,
                                     int K, int N) {
  __shared__ float tile[32][33];
  int bx = blockIdx.x, by = blockIdx.y;
  int tx = threadIdx.x, ty = threadIdx.y;
#pragma unroll
  for (int r = 0; r < 32; r += 8)
    tile[ty + r][tx] = W[(size_t)(by * 32 + ty + r) * N + bx * 32 + tx];
  __syncthreads();
#pragma unroll
  for (int r = 0; r < 32; r += 8)
    Wt[(size_t)(bx * 32 + ty + r) * K + by * 32 + tx] = f2bf(tile[tx][ty + r]);
}

// ---------------- GEMM core (128x128 tile, BK=32, 4 waves, m97-style) ----------------
struct GemmSrc {
  const u16* a0; int sa0;  // A for k <  512
  const u16* a1; int sa1;  // A for k >= 512 (indexed at k-512)
  const u16* b0; int sb0;  // B^T for k <  512
  const u16* b1; int sb1;  // B^T for k >= 512
};

__device__ __forceinline__ void gemm_core(const GemmSrc& S, int brow, int bcol,
                                          int ksteps, u16* As, u16* Bs,
                                          f32x4 acc[4][4]) {
  const int tid = threadIdx.x;
  const int l = tid & 63;
  const int w = tid >> 6;
  const int lr = l >> 2;         // 0..15: row-within-chunk
  const int kl = (l & 3) * 8;    // k offset within BK for staging
  const int rA0 = brow + w * 16 + lr;
  const int rA1 = brow + (w + 4) * 16 + lr;
  const int nB0 = bcol + w * 16 + lr;
  const int nB1 = bcol + (w + 4) * 16 + lr;
  const int wr = w >> 1, wc = w & 1;
  char* AsB = (char*)As;
  char* BsB = (char*)Bs;

  for (int ks = 0; ks < ksteps; ++ks) {
    const int k = ks * 32;
    const u16 *gA0, *gA1, *gB0, *gB1;
    if (k < 512) {
      gA0 = S.a0 + (size_t)rA0 * S.sa0 + (k + kl);
      gA1 = S.a0 + (size_t)rA1 * S.sa0 + (k + kl);
      gB0 = S.b0 + (size_t)nB0 * S.sb0 + (k + kl);
      gB1 = S.b0 + (size_t)nB1 * S.sb0 + (k + kl);
    } else {
      const int kk = k - 512 + kl;
      gA0 = S.a1 + (size_t)rA0 * S.sa1 + kk;
      gA1 = S.a1 + (size_t)rA1 * S.sa1 + kk;
      gB0 = S.b1 + (size_t)nB0 * S.sb1 + kk;
      gB1 = S.b1 + (size_t)nB1 * S.sb1 + kk;
    }
    // A tile: [128][32] bf16 linear; chunk c covers rows [c*16, c*16+16)
    gload_lds16(gA0, AsB + w * 1024);
    gload_lds16(gA1, AsB + (w + 4) * 1024);
    // B tile: [128 n][32 k] bf16 linear (from transposed weights)
    gload_lds16(gB0, BsB + w * 1024);
    gload_lds16(gB1, BsB + (w + 4) * 1024);
    __syncthreads();  // drains vmcnt(0) then barrier

    bf16x8 af[4], bfv[4];
#pragma unroll
    for (int m = 0; m < 4; ++m) {
      int row = wr * 64 + m * 16 + (l & 15);
      af[m] = *(const bf16x8*)(AsB + row * 64 + (l >> 4) * 16);
    }
#pragma unroll
    for (int n = 0; n < 4; ++n) {
      int col = wc * 64 + n * 16 + (l & 15);
      bfv[n] = *(const bf16x8*)(BsB + col * 64 + (l >> 4) * 16);
    }
#pragma unroll
    for (int m = 0; m < 4; ++m)
#pragma unroll
      for (int n = 0; n < 4; ++n)
        acc[m][n] = __builtin_amdgcn_mfma_f32_16x16x32_bf16(af[m], bfv[n], acc[m][n], 0, 0, 0);
    __syncthreads();  // protect LDS before next-iter staging overwrites
  }
}

// ---------------- pass 1: r, z, and a = x@Wxh + bxh ----------------
__global__ __launch_bounds__(256, 2) void gru_pass1(
    const u16* __restrict__ xb, const u16* __restrict__ hb,
    const u16* __restrict__ Wxr_t, const u16* __restrict__ Whr_t,
    const u16* __restrict__ Wxz_t, const u16* __restrict__ Whz_t,
    const u16* __restrict__ Wxh_t,
    const float* __restrict__ bxr, const float* __restrict__ bxz,
    const float* __restrict__ bxh, const float* __restrict__ hidden,
    u16* __restrict__ rhb, u16* __restrict__ zb, float* __restrict__ abuf) {
  __shared__ __align__(16) u16 As[128 * 32];
  __shared__ __align__(16) u16 Bs[128 * 32];
  const int bid = blockIdx.x;
  const int jt = bid % 24;   // N-tile fast-varying: 24 tiles share one A panel
  const int mt = bid / 24;
  const int gate = jt >> 3;          // 0=r, 1=z, 2=a(x-part of candidate)
  const int jcol = (jt & 7) * 128;   // column within gate's 1024
  const int brow = mt * 128;

  GemmSrc S;
  S.a0 = xb;  S.sa0 = INSZ;
  S.a1 = hb;  S.sa1 = HSZ;
  if (gate == 0)      { S.b0 = Wxr_t; S.b1 = Whr_t; }
  else if (gate == 1) { S.b0 = Wxz_t; S.b1 = Whz_t; }
  else                { S.b0 = Wxh_t; S.b1 = Wxh_t; }
  S.sb0 = INSZ; S.sb1 = HSZ;
  const int ksteps = (gate == 2) ? 16 : 48;  // gate2: K=512 only

  f32x4 acc[4][4] = {};
  gemm_core(S, brow, jcol, ksteps, As, Bs, acc);

  const int l = threadIdx.x & 63;
  const int w = threadIdx.x >> 6;
  const int wr = w >> 1, wc = w & 1;
  const int colb = jcol + wc * 64 + (l & 15);
  const int rowb = brow + wr * 64 + (l >> 4) * 4;

  if (gate == 0) {
#pragma unroll
    for (int n = 0; n < 4; ++n) {
      int col = colb + n * 16;
      float bias = bxr[col];
#pragma unroll
      for (int m = 0; m < 4; ++m)
#pragma unroll
        for (int j = 0; j < 4; ++j) {
          int row = rowb + m * 16 + j;
          size_t idx = (size_t)row * HSZ + col;
          float r = 1.f / (1.f + __expf(-(acc[m][n][j] + bias)));
          rhb[idx] = f2bf(r * hidden[idx]);
        }
    }
  } else if (gate == 1) {
#pragma unroll
    for (int n = 0; n < 4; ++n) {
      int col = colb + n * 16;
      float bias = bxz[col];
#pragma unroll
      for (int m = 0; m < 4; ++m)
#pragma unroll
        for (int j = 0; j < 4; ++j) {
          int row = rowb + m * 16 + j;
          size_t idx = (size_t)row * HSZ + col;
          float z = 1.f / (1.f + __expf(-(acc[m][n][j] + bias)));
          zb[idx] = f2bf(z);
        }
    }
  } else {
#pragma unroll
    for (int n = 0; n < 4; ++n) {
      int col = colb + n * 16;
      float bias = bxh[col];
#pragma unroll
      for (int m = 0; m < 4; ++m)
#pragma unroll
        for (int j = 0; j < 4; ++j) {
          int row = rowb + m * 16 + j;
          abuf[(size_t)row * HSZ + col] = acc[m][n][j] + bias;  // f32, into d_out
        }
    }
  }
}

// ---------------- pass 2: out = z*h + (1-z)*tanh((r*h)@Whh + a) ----------------
__global__ __launch_bounds__(256, 2) void gru_pass2(
    const u16* __restrict__ rhb, const u16* __restrict__ Whh_t,
    const u16* __restrict__ zb, const float* __restrict__ hidden,
    float* __restrict__ out) {
  __shared__ __align__(16) u16 As[128 * 32];
  __shared__ __align__(16) u16 Bs[128 * 32];
  const int bid = blockIdx.x;
  const int jt = bid & 7;
  const int mt = bid >> 3;
  const int jcol = jt * 128;
  const int brow = mt * 128;

  GemmSrc S { rhb, HSZ, rhb + 512, HSZ, Whh_t, HSZ, Whh_t + 512, HSZ };
  f32x4 acc[4][4] = {};
  gemm_core(S, brow, jcol, 32, As, Bs, acc);

  const int l = threadIdx.x & 63;
  const int w = threadIdx.x >> 6;
  const int wr = w >> 1, wc = w & 1;
  const int colb = jcol + wc * 64 + (l & 15);
  const int rowb = brow + wr * 64 + (l >> 4) * 4;
#pragma unroll
  for (int n = 0; n < 4; ++n) {
    int col = colb + n * 16;
#pragma unroll
    for (int m = 0; m < 4; ++m)
#pragma unroll
      for (int j = 0; j < 4; ++j) {
        int row = rowb + m * 16 + j;
        size_t idx = (size_t)row * HSZ + col;
        float a = out[idx];  // pass1 gate2 wrote x@Wxh + bxh here
        float e = __expf(2.f * (acc[m][n][j] + a));
        float hc = 1.f - 2.f / (e + 1.f);  // tanh, overflow-safe
        float z = bf2f(zb[idx]);
        float h = hidden[idx];
        out[idx] = z * h + (1.f - z) * hc;
      }
  }
}

extern "C" void kernel_launch(void* const* d_in, const int* in_sizes, int n_in,
                              void* d_out, int out_size, void* d_ws, size_t ws_size,
                              hipStream_t stream) {
  const float* x      = (const float*)d_in[0];
  const float* hidden = (const float*)d_in[1];
  const float* Wxr = (const float*)d_in[2];
  const float* bxr = (const float*)d_in[3];
  const float* Whr = (const float*)d_in[4];
  const float* Wxz = (const float*)d_in[5];
  const float* bxz = (const float*)d_in[6];
  const float* Whz = (const float*)d_in[7];
  const float* Wxh = (const float*)d_in[8];
  const float* bxh = (const float*)d_in[9];
  const float* Whh = (const float*)d_in[10];
  float* out = (float*)d_out;
  (void)in_sizes; (void)n_in; (void)out_size; (void)ws_size;

  char* p = (char*)d_ws;
  u16* xb    = (u16*)p; p += (size_t)B_ROWS * INSZ * 2;
  u16* hb    = (u16*)p; p += (size_t)B_ROWS * HSZ * 2;
  u16* Wxr_t = (u16*)p; p += (size_t)HSZ * INSZ * 2;
  u16* Wxz_t = (u16*)p; p += (size_t)HSZ * INSZ * 2;
  u16* Wxh_t = (u16*)p; p += (size_t)HSZ * INSZ * 2;
  u16* Whr_t = (u16*)p; p += (size_t)HSZ * HSZ * 2;
  u16* Whz_t = (u16*)p; p += (size_t)HSZ * HSZ * 2;
  u16* Whh_t = (u16*)p; p += (size_t)HSZ * HSZ * 2;
  u16* rhb   = (u16*)p; p += (size_t)B_ROWS * HSZ * 2;
  u16* zb    = (u16*)p; p += (size_t)B_ROWS * HSZ * 2;

  const int nx = B_ROWS * INSZ, nh = B_ROWS * HSZ;
  cvt_bf16_kernel<<<(nx / 4 + 255) / 256, 256, 0, stream>>>(x, xb, nx);
  cvt_bf16_kernel<<<(nh / 4 + 255) / 256, 256, 0, stream>>>(hidden, hb, nh);
  transpose_cvt_kernel<<<dim3(HSZ / 32, INSZ / 32), dim3(32, 8), 0, stream>>>(Wxr, Wxr_t, INSZ, HSZ);
  transpose_cvt_kernel<<<dim3(HSZ / 32, INSZ / 32), dim3(32, 8), 0, stream>>>(Wxz, Wxz_t, INSZ, HSZ);
  transpose_cvt_kernel<<<dim3(HSZ / 32, INSZ / 32), dim3(32, 8), 0, stream>>>(Wxh, Wxh_t, INSZ, HSZ);
  transpose_cvt_kernel<<<dim3(HSZ / 32, HSZ / 32), dim3(32, 8), 0, stream>>>(Whr, Whr_t, HSZ, HSZ);
  transpose_cvt_kernel<<<dim3(HSZ / 32, HSZ / 32), dim3(32, 8), 0, stream>>>(Whz, Whz_t, HSZ, HSZ);
  transpose_cvt_kernel<<<dim3(HSZ / 32, HSZ / 32), dim3(32, 8), 0, stream>>>(Whh, Whh_t, HSZ, HSZ);

  gru_pass1<<<128 * 24, 256, 0, stream>>>(xb, hb, Wxr_t, Whr_t, Wxz_t, Whz_t, Wxh_t,
                                          bxr, bxz, bxh, hidden, rhb, zb, out);
  gru_pass2<<<128 * 8, 256, 0, stream>>>(rhb, Whh_t, zb, hidden, out);
}

// Round 2
// 360.137 us; speedup vs baseline: 1.0280x; 1.0280x over previous
//
#include <hip/hip_runtime.h>

typedef unsigned short u16;
typedef unsigned int u32;
typedef __bf16 bf16x8 __attribute__((ext_vector_type(8)));
typedef float f32x4 __attribute__((ext_vector_type(4)));

#define B_ROWS 16384
#define INSZ 512
#define HSZ 1024

__device__ __forceinline__ u16 f2bf(float f) {
  u32 u = __float_as_uint(f);
  u = (u + 0x7fffu + ((u >> 16) & 1u)) >> 16;  // RNE
  return (u16)u;
}
__device__ __forceinline__ float bf2f(u16 b) {
  return __uint_as_float(((u32)b) << 16);
}
__device__ __forceinline__ void gload_lds16(const void* g, void* l) {
  __builtin_amdgcn_global_load_lds((const __attribute__((address_space(1))) void*)g,
                                   (__attribute__((address_space(3))) void*)l,
                                   16, 0, 0);
}

// ---------------- fused converts ----------------
__global__ void cvt2_bf16(const float* __restrict__ x, const float* __restrict__ h,
                          u16* __restrict__ xb, u16* __restrict__ hb) {
  int i = (blockIdx.x * 256 + threadIdx.x) * 4;
  const int nx = B_ROWS * INSZ;
  const float* src;
  u16* dst;
  int j;
  if (i < nx) { src = x; dst = xb; j = i; }
  else        { src = h; dst = hb; j = i - nx; }
  float4 v = *(const float4*)(src + j);
  u32 a = (u32)f2bf(v.x) | ((u32)f2bf(v.y) << 16);
  u32 b = (u32)f2bf(v.z) | ((u32)f2bf(v.w) << 16);
  *(uint2*)(dst + j) = make_uint2(a, b);
}

// all 6 weight transposes in one launch. W: [K][1024] f32 -> Wt: [1024][K] bf16
__global__ void transpose_cvt6(const float* __restrict__ W0, u16* __restrict__ T0,
                               const float* __restrict__ W1, u16* __restrict__ T1,
                               const float* __restrict__ W2, u16* __restrict__ T2,
                               const float* __restrict__ W3, u16* __restrict__ T3,
                               const float* __restrict__ W4, u16* __restrict__ T4,
                               const float* __restrict__ W5, u16* __restrict__ T5) {
  __shared__ float tile[32][33];
  const int z = blockIdx.z;
  const float* W;
  u16* T;
  int K;
  switch (z) {
    case 0: W = W0; T = T0; K = INSZ; break;
    case 1: W = W1; T = T1; K = INSZ; break;
    case 2: W = W2; T = T2; K = INSZ; break;
    case 3: W = W3; T = T3; K = HSZ; break;
    case 4: W = W4; T = T4; K = HSZ; break;
    default: W = W5; T = T5; K = HSZ; break;
  }
  const int bx = blockIdx.x, by = blockIdx.y;
  if (by * 32 >= K) return;
  const int tx = threadIdx.x, ty = threadIdx.y;
#pragma unroll
  for (int r = 0; r < 32; r += 8)
    tile[ty + r][tx] = W[(size_t)(by * 32 + ty + r) * HSZ + bx * 32 + tx];
  __syncthreads();
#pragma unroll
  for (int r = 0; r < 32; r += 8)
    T[(size_t)(bx * 32 + ty + r) * K + by * 32 + tx] = f2bf(tile[tx][ty + r]);
}

// ---------------- 256x256 8-wave, BK=64, 4-phase/K-tile pipelined GEMM ----------------
// LDS per matrix: 2 bufs x [256 rows][64 k] bf16 = 64 KB; A + B = 128 KB.
// Swizzle: LDS(row, blk16) holds global (row, blk16 ^ (row&7)); staged via
// inverse-swizzled GLOBAL source (linear global_load_lds dest, rule 21).
struct Src {
  const u16 *a0, *a1, *b0, *b1;
  int sa0, sa1, sb0, sb1, tsplit;
};

__device__ __forceinline__ const u16* gsrc(const u16* p0, const u16* p1, int s0, int s1,
                                           int tsplit, int t, int grow) {
  return (t < tsplit) ? p0 + (size_t)grow * s0 + t * 64
                      : p1 + (size_t)grow * s1 + (t - tsplit) * 64;
}

// stage one half-tile (128 rows x 64 k = 16 KB) of tile t into buf c.
__device__ __forceinline__ void stage_half(const u16* p0, const u16* p1, int s0, int s1,
                                           int tsplit, int t, int rowbase, int h,
                                           char* matB, int c, int tid, int kswz) {
  char* lds = matB + c * 32768 + h * 16384 + ((tid >> 6) << 10);  // wave-uniform base
  const int r = tid >> 3;  // 0..63
  const u16* g0 = gsrc(p0, p1, s0, s1, tsplit, t, rowbase + h * 128 + r) + kswz;
  const u16* g1 = gsrc(p0, p1, s0, s1, tsplit, t, rowbase + h * 128 + 64 + r) + kswz;
  gload_lds16(g0, lds);
  gload_lds16(g1, lds + 8192);
}

#define STAGE_A(t_, c_, h_) \
  stage_half(S.a0, S.a1, S.sa0, S.sa1, S.tsplit, (t_), brow, (h_), AsB, (c_), tid, kswz)
#define STAGE_B(t_, c_, h_) \
  stage_half(S.b0, S.b1, S.sb0, S.sb1, S.tsplit, (t_), bcol, (h_), BsB, (c_), tid, kswz)

__device__ __forceinline__ void gemm256(const Src& S, int nt, int brow, int bcol,
                                        u16* AsU, u16* BsU, f32x4 acc[8][4]) {
  const int tid = threadIdx.x;
  const int l = tid & 63;
  const int wid = tid >> 6;
  const int wr = wid >> 2, wc = wid & 3;
  const int lr = l & 15, kq = l >> 4;
  const int swzB = (lr & 7) * 16;                        // byte XOR for frag reads
  const int kswz = ((tid & 7) ^ ((tid >> 3) & 7)) * 8;   // element off for staging src
  char* AsB = (char*)AsU;
  char* BsB = (char*)BsU;
  const int colK0 = (kq * 16) ^ swzB;
  const int colK1 = (64 + kq * 16) ^ swzB;
  int aRow[8], bRow[4];
#pragma unroll
  for (int m = 0; m < 8; ++m) aRow[m] = (wr * 128 + m * 16 + lr) * 128;
#pragma unroll
  for (int n = 0; n < 4; ++n) bRow[n] = (wc * 64 + n * 16 + lr) * 128;

  // prologue: tile0 fully + tile1's A-half0 -> 10 loads; wait until tile0 landed.
  STAGE_A(0, 0, 0);
  STAGE_A(0, 0, 1);
  STAGE_B(0, 0, 0);
  STAGE_B(0, 0, 1);
  if (1 < nt) STAGE_A(1, 1, 0);
  asm volatile("s_waitcnt vmcnt(2)" ::: "memory");
  __builtin_amdgcn_s_barrier();
  asm volatile("" ::: "memory");

  for (int t = 0; t < nt; ++t) {
    const int c = t & 1;
    const int cb = c << 15;
    bf16x8 a[4][2], b[4][2];
    // ---------- ph0: read A m0-3 + B n0-1; stage (t+1, A1) ----------
#pragma unroll
    for (int m = 0; m < 4; ++m) {
      a[m][0] = *(const bf16x8*)(AsB + cb + aRow[m] + colK0);
      a[m][1] = *(const bf16x8*)(AsB + cb + aRow[m] + colK1);
    }
#pragma unroll
    for (int n = 0; n < 2; ++n) {
      b[n][0] = *(const bf16x8*)(BsB + cb + bRow[n] + colK0);
      b[n][1] = *(const bf16x8*)(BsB + cb + bRow[n] + colK1);
    }
    if (t + 1 < nt) STAGE_A(t + 1, c ^ 1, 1);
    __builtin_amdgcn_s_barrier();
    asm volatile("s_waitcnt lgkmcnt(0)" ::: "memory");
    __builtin_amdgcn_sched_barrier(0);
    __builtin_amdgcn_s_setprio(1);
#pragma unroll
    for (int kk = 0; kk < 2; ++kk)
#pragma unroll
      for (int m = 0; m < 4; ++m)
#pragma unroll
        for (int n = 0; n < 2; ++n)
          acc[m][n] = __builtin_amdgcn_mfma_f32_16x16x32_bf16(a[m][kk], b[n][kk], acc[m][n], 0, 0, 0);
    __builtin_amdgcn_s_setprio(0);
    __builtin_amdgcn_s_barrier();
    asm volatile("" ::: "memory");
    // ---------- ph1: read B n2-3; stage (t+1, B0) ----------
#pragma unroll
    for (int n = 2; n < 4; ++n) {
      b[n][0] = *(const bf16x8*)(BsB + cb + bRow[n] + colK0);
      b[n][1] = *(const bf16x8*)(BsB + cb + bRow[n] + colK1);
    }
    if (t + 1 < nt) STAGE_B(t + 1, c ^ 1, 0);
    __builtin_amdgcn_s_barrier();
    asm volatile("s_waitcnt lgkmcnt(0)" ::: "memory");
    __builtin_amdgcn_sched_barrier(0);
    __builtin_amdgcn_s_setprio(1);
#pragma unroll
    for (int kk = 0; kk < 2; ++kk)
#pragma unroll
      for (int m = 0; m < 4; ++m)
#pragma unroll
        for (int n = 2; n < 4; ++n)
          acc[m][n] = __builtin_amdgcn_mfma_f32_16x16x32_bf16(a[m][kk], b[n][kk], acc[m][n], 0, 0, 0);
    __builtin_amdgcn_s_setprio(0);
    __builtin_amdgcn_s_barrier();
    asm volatile("" ::: "memory");
    // ---------- ph2: read A m4-7; stage (t+1, B1) ----------
#pragma unroll
    for (int m = 0; m < 4; ++m) {
      a[m][0] = *(const bf16x8*)(AsB + cb + aRow[m + 4] + colK0);
      a[m][1] = *(const bf16x8*)(AsB + cb + aRow[m + 4] + colK1);
    }
    if (t + 1 < nt) STAGE_B(t + 1, c ^ 1, 1);
    __builtin_amdgcn_s_barrier();
    asm volatile("s_waitcnt lgkmcnt(0)" ::: "memory");
    __builtin_amdgcn_sched_barrier(0);
    __builtin_amdgcn_s_setprio(1);
#pragma unroll
    for (int kk = 0; kk < 2; ++kk)
#pragma unroll
      for (int m = 0; m < 4; ++m)
#pragma unroll
        for (int n = 2; n < 4; ++n)
          acc[m + 4][n] = __builtin_amdgcn_mfma_f32_16x16x32_bf16(a[m][kk], b[n][kk], acc[m + 4][n], 0, 0, 0);
    __builtin_amdgcn_s_setprio(0);
    __builtin_amdgcn_s_barrier();
    asm volatile("" ::: "memory");
    // ---------- ph3: stage (t+2, A0) into buf c; counted vmcnt ----------
    if (t + 2 < nt) STAGE_A(t + 2, c, 0);
    __builtin_amdgcn_s_barrier();
    __builtin_amdgcn_s_setprio(1);
#pragma unroll
    for (int kk = 0; kk < 2; ++kk)
#pragma unroll
      for (int m = 0; m < 4; ++m)
#pragma unroll
        for (int n = 0; n < 2; ++n)
          acc[m + 4][n] = __builtin_amdgcn_mfma_f32_16x16x32_bf16(a[m][kk], b[n][kk], acc[m + 4][n], 0, 0, 0);
    __builtin_amdgcn_s_setprio(0);
    if (t + 2 < nt) { asm volatile("s_waitcnt vmcnt(2)" ::: "memory"); }
    else            { asm volatile("s_waitcnt vmcnt(0)" ::: "memory"); }
    __builtin_amdgcn_s_barrier();
    asm volatile("" ::: "memory");
  }
}

// ---------------- pass 1: r, z, a = x@Wxh + bxh ----------------
__global__ __launch_bounds__(512, 2) void gru_pass1(
    const u16* __restrict__ xb, const u16* __restrict__ hb,
    const u16* __restrict__ Wxr_t, const u16* __restrict__ Whr_t,
    const u16* __restrict__ Wxz_t, const u16* __restrict__ Whz_t,
    const u16* __restrict__ Wxh_t,
    const float* __restrict__ bxr, const float* __restrict__ bxz,
    const float* __restrict__ bxh, const float* __restrict__ hidden,
    u16* __restrict__ rhb, u16* __restrict__ zb, float* __restrict__ abuf) {
  __shared__ __align__(16) u16 As[2 * 256 * 64];
  __shared__ __align__(16) u16 Bs[2 * 256 * 64];
  // bijective XCD swizzle (768 % 8 == 0), mt fast within jt -> weight panel in L2
  const int orig = blockIdx.x;
  const int wg = (orig & 7) * 96 + (orig >> 3);
  const int mt = wg & 63, jt = wg >> 6;
  const int gate = jt >> 2;
  const int jcol = (jt & 3) * 256;
  const int brow = mt * 256;

  Src S;
  S.a0 = xb; S.sa0 = INSZ; S.a1 = hb; S.sa1 = HSZ; S.tsplit = 8;
  S.sb0 = INSZ; S.sb1 = HSZ;
  int nt;
  if (gate == 0)      { S.b0 = Wxr_t; S.b1 = Whr_t; nt = 24; }
  else if (gate == 1) { S.b0 = Wxz_t; S.b1 = Whz_t; nt = 24; }
  else                { S.b0 = Wxh_t; S.b1 = Wxh_t; nt = 8; }

  f32x4 acc[8][4] = {};
  gemm256(S, nt, brow, jcol, As, Bs, acc);

  const int l = threadIdx.x & 63;
  const int wid = threadIdx.x >> 6;
  const int wr = wid >> 2, wc = wid & 3;
  const int colb = jcol + wc * 64 + (l & 15);
  const int rowb = brow + wr * 128 + (l >> 4) * 4;
  if (gate == 0) {
#pragma unroll
    for (int n = 0; n < 4; ++n) {
      const int col = colb + n * 16;
      const float bias = bxr[col];
#pragma unroll
      for (int m = 0; m < 8; ++m)
#pragma unroll
        for (int j = 0; j < 4; ++j) {
          const int row = rowb + m * 16 + j;
          const size_t idx = (size_t)row * HSZ + col;
          const float r = 1.f / (1.f + __expf(-(acc[m][n][j] + bias)));
          rhb[idx] = f2bf(r * hidden[idx]);
        }
    }
  } else if (gate == 1) {
#pragma unroll
    for (int n = 0; n < 4; ++n) {
      const int col = colb + n * 16;
      const float bias = bxz[col];
#pragma unroll
      for (int m = 0; m < 8; ++m)
#pragma unroll
        for (int j = 0; j < 4; ++j) {
          const int row = rowb + m * 16 + j;
          const size_t idx = (size_t)row * HSZ + col;
          const float z = 1.f / (1.f + __expf(-(acc[m][n][j] + bias)));
          zb[idx] = f2bf(z);
        }
    }
  } else {
#pragma unroll
    for (int n = 0; n < 4; ++n) {
      const int col = colb + n * 16;
      const float bias = bxh[col];
#pragma unroll
      for (int m = 0; m < 8; ++m)
#pragma unroll
        for (int j = 0; j < 4; ++j) {
          const int row = rowb + m * 16 + j;
          abuf[(size_t)row * HSZ + col] = acc[m][n][j] + bias;  // f32, into d_out
        }
    }
  }
}

// ---------------- pass 2: out = z*h + (1-z)*tanh((r*h)@Whh + a) ----------------
__global__ __launch_bounds__(512, 2) void gru_pass2(
    const u16* __restrict__ rhb, const u16* __restrict__ Whh_t,
    const u16* __restrict__ zb, const float* __restrict__ hidden,
    float* __restrict__ out) {
  __shared__ __align__(16) u16 As[2 * 256 * 64];
  __shared__ __align__(16) u16 Bs[2 * 256 * 64];
  const int orig = blockIdx.x;
  const int wg = (orig & 7) * 32 + (orig >> 3);  // 256 % 8 == 0
  const int mt = wg & 63, jt = wg >> 6;
  const int jcol = jt * 256;
  const int brow = mt * 256;

  Src S;
  S.a0 = rhb; S.sa0 = HSZ; S.a1 = rhb; S.sa1 = HSZ; S.tsplit = 16;
  S.b0 = Whh_t; S.sb0 = HSZ; S.b1 = Whh_t; S.sb1 = HSZ;

  f32x4 acc[8][4] = {};
  gemm256(S, 16, brow, jcol, As, Bs, acc);

  const int l = threadIdx.x & 63;
  const int wid = threadIdx.x >> 6;
  const int wr = wid >> 2, wc = wid & 3;
  const int colb = jcol + wc * 64 + (l & 15);
  const int rowb = brow + wr * 128 + (l >> 4) * 4;
#pragma unroll
  for (int n = 0; n < 4; ++n) {
    const int col = colb + n * 16;
#pragma unroll
    for (int m = 0; m < 8; ++m)
#pragma unroll
      for (int j = 0; j < 4; ++j) {
        const int row = rowb + m * 16 + j;
        const size_t idx = (size_t)row * HSZ + col;
        const float aa = out[idx];  // pass1 gate2 wrote x@Wxh + bxh here
        const float e = __expf(2.f * (acc[m][n][j] + aa));
        const float hc = 1.f - 2.f / (e + 1.f);  // tanh, overflow-safe
        const float z = bf2f(zb[idx]);
        const float h = hidden[idx];
        out[idx] = z * h + (1.f - z) * hc;
      }
  }
}

extern "C" void kernel_launch(void* const* d_in, const int* in_sizes, int n_in,
                              void* d_out, int out_size, void* d_ws, size_t ws_size,
                              hipStream_t stream) {
  const float* x      = (const float*)d_in[0];
  const float* hidden = (const float*)d_in[1];
  const float* Wxr = (const float*)d_in[2];
  const float* bxr = (const float*)d_in[3];
  const float* Whr = (const float*)d_in[4];
  const float* Wxz = (const float*)d_in[5];
  const float* bxz = (const float*)d_in[6];
  const float* Whz = (const float*)d_in[7];
  const float* Wxh = (const float*)d_in[8];
  const float* bxh = (const float*)d_in[9];
  const float* Whh = (const float*)d_in[10];
  float* out = (float*)d_out;
  (void)in_sizes; (void)n_in; (void)out_size; (void)ws_size;

  char* p = (char*)d_ws;
  u16* xb    = (u16*)p; p += (size_t)B_ROWS * INSZ * 2;
  u16* hb    = (u16*)p; p += (size_t)B_ROWS * HSZ * 2;
  u16* Wxr_t = (u16*)p; p += (size_t)HSZ * INSZ * 2;
  u16* Wxz_t = (u16*)p; p += (size_t)HSZ * INSZ * 2;
  u16* Wxh_t = (u16*)p; p += (size_t)HSZ * INSZ * 2;
  u16* Whr_t = (u16*)p; p += (size_t)HSZ * HSZ * 2;
  u16* Whz_t = (u16*)p; p += (size_t)HSZ * HSZ * 2;
  u16* Whh_t = (u16*)p; p += (size_t)HSZ * HSZ * 2;
  u16* rhb   = (u16*)p; p += (size_t)B_ROWS * HSZ * 2;
  u16* zb    = (u16*)p; p += (size_t)B_ROWS * HSZ * 2;

  const int ntot = B_ROWS * (INSZ + HSZ);
  cvt2_bf16<<<ntot / 4 / 256, 256, 0, stream>>>(x, hidden, xb, hb);
  transpose_cvt6<<<dim3(32, 32, 6), dim3(32, 8), 0, stream>>>(
      Wxr, Wxr_t, Wxz, Wxz_t, Wxh, Wxh_t, Whr, Whr_t, Whz, Whz_t, Whh, Whh_t);

  gru_pass1<<<768, 512, 0, stream>>>(xb, hb, Wxr_t, Whr_t, Wxz_t, Whz_t, Wxh_t,
                                     bxr, bxz, bxh, hidden, rhb, zb, out);
  gru_pass2<<<256, 512, 0, stream>>>(rhb, Whh_t, zb, hidden, out);
}

// Round 3
// 294.130 us; speedup vs baseline: 1.2587x; 1.2244x over previous
//
#include <hip/hip_runtime.h>

typedef unsigned short u16;
typedef unsigned int u32;
typedef __bf16 bf16x8 __attribute__((ext_vector_type(8)));
typedef float f32x4 __attribute__((ext_vector_type(4)));

#define B_ROWS 16384
#define K1 1536

__device__ __forceinline__ u16 f2bf(float f) {
  u32 u = __float_as_uint(f);
  u = (u + 0x7fffu + ((u >> 16) & 1u)) >> 16;  // RNE
  return (u16)u;
}
__device__ __forceinline__ float bf2f(u16 b) {
  return __uint_as_float(((u32)b) << 16);
}
__device__ __forceinline__ void gload_lds16(const void* g, void* l) {
  __builtin_amdgcn_global_load_lds((const __attribute__((address_space(1))) void*)g,
                                   (__attribute__((address_space(3))) void*)l,
                                   16, 0, 0);
}

// ---------------- convert: xh = [bf16(x) | bf16(h)]  (16384 x 1536) ----------------
__global__ void cvt_xh(const float* __restrict__ x, const float* __restrict__ h,
                       u16* __restrict__ xh) {
  const int iv = blockIdx.x * 256 + threadIdx.x;  // float4-group id
  const int row = iv / 384;
  const int col = (iv - row * 384) * 4;
  const float* src = (col < 512) ? x + (size_t)row * 512 + col
                                 : h + (size_t)row * 1024 + (col - 512);
  float4 v = *(const float4*)src;
  u32 a = (u32)f2bf(v.x) | ((u32)f2bf(v.y) << 16);
  u32 b = (u32)f2bf(v.z) | ((u32)f2bf(v.w) << 16);
  *(uint2*)(xh + (size_t)row * 1536 + col) = make_uint2(a, b);
}

// ---------------- weight transposes into concatenated B^T panels ----------------
// W1t [2048][1536] = [[Wxr^T Whr^T],[Wxz^T Whz^T]]; W2t [1024][1536] = [Wxh^T Whh^T]
__global__ void transpose_cvt6(const float* __restrict__ Wxr, const float* __restrict__ Whr,
                               const float* __restrict__ Wxz, const float* __restrict__ Whz,
                               const float* __restrict__ Wxh, const float* __restrict__ Whh,
                               u16* __restrict__ W1t, u16* __restrict__ W2t) {
  __shared__ float tile[32][33];
  const int z = blockIdx.z;
  const float* W;
  u16* T;
  int Ks, koff, roff;
  switch (z) {
    case 0:  W = Wxr; T = W1t; Ks = 512;  koff = 0;   roff = 0;    break;
    case 1:  W = Whr; T = W1t; Ks = 1024; koff = 512; roff = 0;    break;
    case 2:  W = Wxz; T = W1t; Ks = 512;  koff = 0;   roff = 1024; break;
    case 3:  W = Whz; T = W1t; Ks = 1024; koff = 512; roff = 1024; break;
    case 4:  W = Wxh; T = W2t; Ks = 512;  koff = 0;   roff = 0;    break;
    default: W = Whh; T = W2t; Ks = 1024; koff = 512; roff = 0;    break;
  }
  const int bx = blockIdx.x, by = blockIdx.y;
  if (by * 32 >= Ks) return;
  const int tx = threadIdx.x, ty = threadIdx.y;
#pragma unroll
  for (int r = 0; r < 32; r += 8)
    tile[ty + r][tx] = W[(size_t)(by * 32 + ty + r) * 1024 + bx * 32 + tx];
  __syncthreads();
#pragma unroll
  for (int r = 0; r < 32; r += 8)
    T[(size_t)(roff + bx * 32 + ty + r) * K1 + koff + by * 32 + tx] = f2bf(tile[tx][ty + r]);
}

// ---------------- 256x256 8-wave, BK=64 pipelined GEMM (R2-verified core) ----------------
struct Src {
  const u16 *a0, *a1, *b0, *b1;
  int sa0, sa1, sb0, sb1, tsplit;
};

__device__ __forceinline__ const u16* gsrc(const u16* p0, const u16* p1, int s0, int s1,
                                           int tsplit, int t, int grow) {
  return (t < tsplit) ? p0 + (size_t)grow * s0 + t * 64
                      : p1 + (size_t)grow * s1 + (t - tsplit) * 64;
}

__device__ __forceinline__ void stage_half(const u16* p0, const u16* p1, int s0, int s1,
                                           int tsplit, int t, int rowbase, int h,
                                           char* matB, int c, int tid, int kswz) {
  char* lds = matB + c * 32768 + h * 16384 + ((tid >> 6) << 10);  // wave-uniform base
  const int r = tid >> 3;  // 0..63
  const u16* g0 = gsrc(p0, p1, s0, s1, tsplit, t, rowbase + h * 128 + r) + kswz;
  const u16* g1 = gsrc(p0, p1, s0, s1, tsplit, t, rowbase + h * 128 + 64 + r) + kswz;
  gload_lds16(g0, lds);
  gload_lds16(g1, lds + 8192);
}

#define STAGE_A(t_, c_, h_) \
  stage_half(S.a0, S.a1, S.sa0, S.sa1, S.tsplit, (t_), brow, (h_), AsB, (c_), tid, kswz)
#define STAGE_B(t_, c_, h_) \
  stage_half(S.b0, S.b1, S.sb0, S.sb1, S.tsplit, (t_), bcol, (h_), BsB, (c_), tid, kswz)

__device__ __forceinline__ void gemm256(const Src& S, int nt, int brow, int bcol,
                                        u16* AsU, u16* BsU, f32x4 acc[8][4]) {
  const int tid = threadIdx.x;
  const int l = tid & 63;
  const int wid = tid >> 6;
  const int wr = wid >> 2, wc = wid & 3;
  const int lr = l & 15, kq = l >> 4;
  const int swzB = (lr & 7) * 16;                        // byte XOR for frag reads
  const int kswz = ((tid & 7) ^ ((tid >> 3) & 7)) * 8;   // element off for staging src
  char* AsB = (char*)AsU;
  char* BsB = (char*)BsU;
  const int colK0 = (kq * 16) ^ swzB;
  const int colK1 = (64 + kq * 16) ^ swzB;
  int aRow[8], bRow[4];
#pragma unroll
  for (int m = 0; m < 8; ++m) aRow[m] = (wr * 128 + m * 16 + lr) * 128;
#pragma unroll
  for (int n = 0; n < 4; ++n) bRow[n] = (wc * 64 + n * 16 + lr) * 128;

  // prologue: tile0 fully + tile1's A-half0
  STAGE_A(0, 0, 0);
  STAGE_A(0, 0, 1);
  STAGE_B(0, 0, 0);
  STAGE_B(0, 0, 1);
  if (1 < nt) STAGE_A(1, 1, 0);
  asm volatile("s_waitcnt vmcnt(2)" ::: "memory");
  __builtin_amdgcn_s_barrier();
  asm volatile("" ::: "memory");

  for (int t = 0; t < nt; ++t) {
    const int c = t & 1;
    const int cb = c << 15;
    bf16x8 a[4][2], b[4][2];
    // ---------- ph0: read A m0-3 + B n0-1; stage (t+1, A1) ----------
#pragma unroll
    for (int m = 0; m < 4; ++m) {
      a[m][0] = *(const bf16x8*)(AsB + cb + aRow[m] + colK0);
      a[m][1] = *(const bf16x8*)(AsB + cb + aRow[m] + colK1);
    }
#pragma unroll
    for (int n = 0; n < 2; ++n) {
      b[n][0] = *(const bf16x8*)(BsB + cb + bRow[n] + colK0);
      b[n][1] = *(const bf16x8*)(BsB + cb + bRow[n] + colK1);
    }
    if (t + 1 < nt) STAGE_A(t + 1, c ^ 1, 1);
    __builtin_amdgcn_s_barrier();
    asm volatile("s_waitcnt lgkmcnt(0)" ::: "memory");
    __builtin_amdgcn_sched_barrier(0);
    __builtin_amdgcn_s_setprio(1);
#pragma unroll
    for (int kk = 0; kk < 2; ++kk)
#pragma unroll
      for (int m = 0; m < 4; ++m)
#pragma unroll
        for (int n = 0; n < 2; ++n)
          acc[m][n] = __builtin_amdgcn_mfma_f32_16x16x32_bf16(a[m][kk], b[n][kk], acc[m][n], 0, 0, 0);
    __builtin_amdgcn_s_setprio(0);
    __builtin_amdgcn_s_barrier();
    asm volatile("" ::: "memory");
    // ---------- ph1: read B n2-3; stage (t+1, B0) ----------
#pragma unroll
    for (int n = 2; n < 4; ++n) {
      b[n][0] = *(const bf16x8*)(BsB + cb + bRow[n] + colK0);
      b[n][1] = *(const bf16x8*)(BsB + cb + bRow[n] + colK1);
    }
    if (t + 1 < nt) STAGE_B(t + 1, c ^ 1, 0);
    __builtin_amdgcn_s_barrier();
    asm volatile("s_waitcnt lgkmcnt(0)" ::: "memory");
    __builtin_amdgcn_sched_barrier(0);
    __builtin_amdgcn_s_setprio(1);
#pragma unroll
    for (int kk = 0; kk < 2; ++kk)
#pragma unroll
      for (int m = 0; m < 4; ++m)
#pragma unroll
        for (int n = 2; n < 4; ++n)
          acc[m][n] = __builtin_amdgcn_mfma_f32_16x16x32_bf16(a[m][kk], b[n][kk], acc[m][n], 0, 0, 0);
    __builtin_amdgcn_s_setprio(0);
    __builtin_amdgcn_s_barrier();
    asm volatile("" ::: "memory");
    // ---------- ph2: read A m4-7; stage (t+1, B1) ----------
#pragma unroll
    for (int m = 0; m < 4; ++m) {
      a[m][0] = *(const bf16x8*)(AsB + cb + aRow[m + 4] + colK0);
      a[m][1] = *(const bf16x8*)(AsB + cb + aRow[m + 4] + colK1);
    }
    if (t + 1 < nt) STAGE_B(t + 1, c ^ 1, 1);
    __builtin_amdgcn_s_barrier();
    asm volatile("s_waitcnt lgkmcnt(0)" ::: "memory");
    __builtin_amdgcn_sched_barrier(0);
    __builtin_amdgcn_s_setprio(1);
#pragma unroll
    for (int kk = 0; kk < 2; ++kk)
#pragma unroll
      for (int m = 0; m < 4; ++m)
#pragma unroll
        for (int n = 2; n < 4; ++n)
          acc[m + 4][n] = __builtin_amdgcn_mfma_f32_16x16x32_bf16(a[m][kk], b[n][kk], acc[m + 4][n], 0, 0, 0);
    __builtin_amdgcn_s_setprio(0);
    __builtin_amdgcn_s_barrier();
    asm volatile("" ::: "memory");
    // ---------- ph3: stage (t+2, A0); counted vmcnt ----------
    if (t + 2 < nt) STAGE_A(t + 2, c, 0);
    __builtin_amdgcn_s_barrier();
    __builtin_amdgcn_s_setprio(1);
#pragma unroll
    for (int kk = 0; kk < 2; ++kk)
#pragma unroll
      for (int m = 0; m < 4; ++m)
#pragma unroll
        for (int n = 0; n < 2; ++n)
          acc[m + 4][n] = __builtin_amdgcn_mfma_f32_16x16x32_bf16(a[m][kk], b[n][kk], acc[m + 4][n], 0, 0, 0);
    __builtin_amdgcn_s_setprio(0);
    if (t + 2 < nt) { asm volatile("s_waitcnt vmcnt(2)" ::: "memory"); }
    else            { asm volatile("s_waitcnt vmcnt(0)" ::: "memory"); }
    __builtin_amdgcn_s_barrier();
    asm volatile("" ::: "memory");
  }
}

// ---------------- GEMM1: [x|h] @ W1 -> r (writes r*h bf16), z (bf16) ----------------
__global__ __launch_bounds__(512, 2) void gru_gemm1(
    const u16* __restrict__ xh, const u16* __restrict__ W1t,
    const float* __restrict__ bxr, const float* __restrict__ bxz,
    u16* __restrict__ rhb, u16* __restrict__ zb) {
  __shared__ __align__(16) u16 As[2 * 256 * 64];
  __shared__ __align__(16) u16 Bs[2 * 256 * 64];
  const int orig = blockIdx.x;                   // 512 blocks, 512 % 8 == 0
  const int wg = (orig & 7) * 64 + (orig >> 3);  // bijective XCD swizzle
  const int mt = wg & 63, jt = wg >> 6;          // mt fast: 64 blocks share B panel
  const int brow = mt * 256;
  const int jcol = jt * 256;                     // within N=2048

  Src S;
  S.a0 = xh;  S.sa0 = K1; S.a1 = xh + 512;  S.sa1 = K1;
  S.b0 = W1t; S.sb0 = K1; S.b1 = W1t + 512; S.sb1 = K1;
  S.tsplit = 8;

  f32x4 acc[8][4] = {};
  gemm256(S, 24, brow, jcol, As, Bs, acc);

  const int l = threadIdx.x & 63;
  const int wid = threadIdx.x >> 6;
  const int wr = wid >> 2, wc = wid & 3;
  const int colb = jcol + wc * 64 + (l & 15);
  const int rowb = brow + wr * 128 + (l >> 4) * 4;
  if (jt < 4) {  // reset gate -> store r*h (bf16)
#pragma unroll
    for (int n = 0; n < 4; ++n) {
      const int col = colb + n * 16;
      const float bias = bxr[col];
#pragma unroll
      for (int m = 0; m < 8; ++m)
#pragma unroll
        for (int j = 0; j < 4; ++j) {
          const int row = rowb + m * 16 + j;
          const float rg = 1.f / (1.f + __expf(-(acc[m][n][j] + bias)));
          const float hv = bf2f(xh[(size_t)row * K1 + 512 + col]);
          rhb[(size_t)row * 1024 + col] = f2bf(rg * hv);
        }
    }
  } else {  // update gate -> store z (bf16)
#pragma unroll
    for (int n = 0; n < 4; ++n) {
      const int col = colb + n * 16 - 1024;
      const float bias = bxz[col];
#pragma unroll
      for (int m = 0; m < 8; ++m)
#pragma unroll
        for (int j = 0; j < 4; ++j) {
          const int row = rowb + m * 16 + j;
          const float zg = 1.f / (1.f + __expf(-(acc[m][n][j] + bias)));
          zb[(size_t)row * 1024 + col] = f2bf(zg);
        }
    }
  }
}

// ---------------- GEMM2: [x|r*h] @ W2 -> out = z*h + (1-z)*tanh(acc + bxh) ----------------
__global__ __launch_bounds__(512, 2) void gru_gemm2(
    const u16* __restrict__ xh, const u16* __restrict__ rhb,
    const u16* __restrict__ W2t, const float* __restrict__ bxh,
    const u16* __restrict__ zb, const float* __restrict__ hidden,
    float* __restrict__ out) {
  __shared__ __align__(16) u16 As[2 * 256 * 64];
  __shared__ __align__(16) u16 Bs[2 * 256 * 64];
  const int orig = blockIdx.x;                   // 256 blocks, 256 % 8 == 0
  const int wg = (orig & 7) * 32 + (orig >> 3);
  const int mt = wg & 63, jt = wg >> 6;          // jt 0..3
  const int brow = mt * 256;
  const int jcol = jt * 256;

  Src S;
  S.a0 = xh;  S.sa0 = K1; S.a1 = rhb;       S.sa1 = 1024;
  S.b0 = W2t; S.sb0 = K1; S.b1 = W2t + 512; S.sb1 = K1;
  S.tsplit = 8;

  f32x4 acc[8][4] = {};
  gemm256(S, 24, brow, jcol, As, Bs, acc);

  const int l = threadIdx.x & 63;
  const int wid = threadIdx.x >> 6;
  const int wr = wid >> 2, wc = wid & 3;
  const int colb = jcol + wc * 64 + (l & 15);
  const int rowb = brow + wr * 128 + (l >> 4) * 4;
#pragma unroll
  for (int n = 0; n < 4; ++n) {
    const int col = colb + n * 16;
    const float bias = bxh[col];
#pragma unroll
    for (int m = 0; m < 8; ++m)
#pragma unroll
      for (int j = 0; j < 4; ++j) {
        const int row = rowb + m * 16 + j;
        const size_t idx = (size_t)row * 1024 + col;
        const float e = __expf(2.f * (acc[m][n][j] + bias));
        const float hc = 1.f - 2.f / (e + 1.f);  // tanh, overflow-safe
        const float z = bf2f(zb[idx]);
        const float h = hidden[idx];
        out[idx] = z * h + (1.f - z) * hc;
      }
  }
}

extern "C" void kernel_launch(void* const* d_in, const int* in_sizes, int n_in,
                              void* d_out, int out_size, void* d_ws, size_t ws_size,
                              hipStream_t stream) {
  const float* x      = (const float*)d_in[0];
  const float* hidden = (const float*)d_in[1];
  const float* Wxr = (const float*)d_in[2];
  const float* bxr = (const float*)d_in[3];
  const float* Whr = (const float*)d_in[4];
  const float* Wxz = (const float*)d_in[5];
  const float* bxz = (const float*)d_in[6];
  const float* Whz = (const float*)d_in[7];
  const float* Wxh = (const float*)d_in[8];
  const float* bxh = (const float*)d_in[9];
  const float* Whh = (const float*)d_in[10];
  float* out = (float*)d_out;
  (void)in_sizes; (void)n_in; (void)out_size; (void)ws_size;

  char* p = (char*)d_ws;
  u16* xh  = (u16*)p; p += (size_t)B_ROWS * K1 * 2;        // 48 MB
  u16* W1t = (u16*)p; p += (size_t)2048 * K1 * 2;          // 6 MB
  u16* W2t = (u16*)p; p += (size_t)1024 * K1 * 2;          // 3 MB
  u16* rhb = (u16*)p; p += (size_t)B_ROWS * 1024 * 2;      // 32 MB
  u16* zb  = (u16*)p; p += (size_t)B_ROWS * 1024 * 2;      // 32 MB

  cvt_xh<<<B_ROWS * 384 / 256, 256, 0, stream>>>(x, hidden, xh);
  transpose_cvt6<<<dim3(32, 32, 6), dim3(32, 8), 0, stream>>>(
      Wxr, Whr, Wxz, Whz, Wxh, Whh, W1t, W2t);

  gru_gemm1<<<512, 512, 0, stream>>>(xh, W1t, bxr, bxz, rhb, zb);
  gru_gemm2<<<256, 512, 0, stream>>>(xh, rhb, W2t, bxh, zb, hidden, out);
}